// Round 8
// baseline (552.569 us; speedup 1.0000x reference)
//
#include <hip/hip_runtime.h>

// ---------------------------------------------------------------------------
// GCN forward. Hot-path design (R4-R7 evidence):
//  - agg is issue/latency-bound on gather instructions (count = NCH*E/segs);
//    use 8 chunks x float2 x TPN=8: 0.8M gather instrs (R7-level) AND 2.8MB
//    L2-resident slice (R6-level FETCH). chunk = blockIdx & 7 -> XCD-pinned.
//  - histogram atomics ping-pong lines across XCDs -> 8 shadow copies
//    (shadow = blockIdx & 7, XCD-local) + 8-way reduce. Shadows alias bufA.
//  - edge (col,norm) packed i64, broadcast-loaded (no shfl); A-stores NT.
// ---------------------------------------------------------------------------

#define BT 256
#define SCAN_B 256

// ---------------- shadowed histogram ----------------
__global__ void zero8_kernel(float* buf, int n16) {  // counts8+wsum8 = 16N elems
    int i = blockIdx.x * blockDim.x + threadIdx.x;
    if (i < n16) buf[i] = 0.f;
}

__global__ void hist8_kernel(const int* __restrict__ row, const float* __restrict__ w,
                             int* counts8, float* wsum8, int n, int e) {
    int i = blockIdx.x * blockDim.x + threadIdx.x;
    if (i >= e) return;
    int s = blockIdx.x & 7;  // shadow pinned to one XCD under round-robin dispatch
    int r = row[i];
    atomicAdd(&counts8[s * n + r], 1);
    unsafeAtomicAdd(&wsum8[s * n + r], w[i]);
}

__global__ void reduce8_kernel(const int* __restrict__ counts8, const float* __restrict__ wsum8,
                               int* __restrict__ counts, float* __restrict__ deg, int n) {
    int i = blockIdx.x * blockDim.x + threadIdx.x;
    if (i >= n) return;
    int c = 0;
    float ws = 1.0f;  // self-loop weight
#pragma unroll
    for (int s = 0; s < 8; ++s) {
        c += counts8[s * n + i];
        ws += wsum8[s * n + i];
    }
    counts[i] = c;
    deg[i] = ws;
}

// exclusive scan of counts (in rowptr[0..n-1]); also deg -> dis in-place
__global__ void scan1_kernel(int* counts, int* bsums, float* deg, int n) {
    __shared__ int s[SCAN_B];
    int t = threadIdx.x;
    int i = blockIdx.x * SCAN_B + t;
    int v = (i < n) ? counts[i] : 0;
    s[t] = v;
    __syncthreads();
    for (int off = 1; off < SCAN_B; off <<= 1) {
        int x = (t >= off) ? s[t - off] : 0;
        __syncthreads();
        s[t] += x;
        __syncthreads();
    }
    if (i < n) {
        counts[i] = s[t] - v;  // exclusive
        float d = deg[i];
        deg[i] = (d > 0.f) ? rsqrtf(fmaxf(d, 1e-12f)) : 0.f;
    }
    if (t == SCAN_B - 1) bsums[blockIdx.x] = s[t];
}

__global__ void scan2_kernel(int* bsums, int nb) {  // single block, nb <= SCAN_B
    __shared__ int s[SCAN_B];
    int t = threadIdx.x;
    int v = (t < nb) ? bsums[t] : 0;
    s[t] = v;
    __syncthreads();
    for (int off = 1; off < SCAN_B; off <<= 1) {
        int x = (t >= off) ? s[t - off] : 0;
        __syncthreads();
        s[t] += x;
        __syncthreads();
    }
    if (t < nb) bsums[t] = s[t] - v;
}

__global__ void scan3_kernel(int* rowptr, const int* __restrict__ bsums, int* cursor,
                             int n, int e) {
    int i = blockIdx.x * blockDim.x + threadIdx.x;
    if (i < n) {
        int rp = rowptr[i] + bsums[i / SCAN_B];
        rowptr[i] = rp;
        cursor[i] = rp;
    }
    if (i == 0) rowptr[n] = e;
}

__global__ void fill_kernel(const int* __restrict__ row, const int* __restrict__ col,
                            const float* __restrict__ w, const float* __restrict__ dis,
                            int* cursor, long long* __restrict__ epack, int e) {
    int i = blockIdx.x * blockDim.x + threadIdx.x;
    if (i >= e) return;
    int r = row[i], c = col[i];
    float nv = dis[r] * w[i] * dis[c];
    int dst = atomicAdd(&cursor[r], 1);
    long long v = ((long long)__float_as_int(nv) << 32) | (unsigned int)c;
    __builtin_nontemporal_store(v, &epack[dst]);
}

// ---------------- register-tiled GEMM: Hc = chunked(actin(X) @ W) ------------
// X row-major [n,K] (K%4==0); output chunked Hc[c/CHW][n][c%CHW].
template <int K, int F, int CHW, bool RELU_IN>
__global__ __launch_bounds__(256) void gemm_tile_kernel(const float* __restrict__ X,
                                                        const float* __restrict__ W,
                                                        float* __restrict__ Hc, int n) {
    static_assert(K % 4 == 0, "K must be multiple of 4");
    constexpr int NCG = (F + 3) / 4;
    constexpr int FP = NCG * 4;
    constexpr int RG = 256 / NCG;
    constexpr int ROWS = RG * 4;

    __shared__ float Ws[K * FP];
    const int tid = threadIdx.x;
    for (int i = tid; i < K * FP; i += 256) {
        int k = i / FP, c = i - k * FP;
        Ws[i] = (c < F) ? W[k * F + c] : 0.f;
    }
    __syncthreads();

    const int txc = tid % NCG;
    const int tyr = tid / NCG;
    if (tyr >= RG) return;

    const int r0 = blockIdx.x * ROWS + tyr * 4;
    bool rv[4];
    const float* xrow[4];
#pragma unroll
    for (int i = 0; i < 4; ++i) {
        int r = r0 + i;
        rv[i] = (r < n);
        xrow[i] = X + (long long)(rv[i] ? r : 0) * K;
    }

    float acc[4][4] = {};
    const float* wbase = &Ws[txc * 4];
    for (int k = 0; k < K; k += 4) {
        float4 w0 = *reinterpret_cast<const float4*>(wbase + (k + 0) * FP);
        float4 w1 = *reinterpret_cast<const float4*>(wbase + (k + 1) * FP);
        float4 w2 = *reinterpret_cast<const float4*>(wbase + (k + 2) * FP);
        float4 w3 = *reinterpret_cast<const float4*>(wbase + (k + 3) * FP);
#pragma unroll
        for (int i = 0; i < 4; ++i) {
            float4 x4 = *reinterpret_cast<const float4*>(xrow[i] + k);
            if (RELU_IN) {
                x4.x = fmaxf(x4.x, 0.f); x4.y = fmaxf(x4.y, 0.f);
                x4.z = fmaxf(x4.z, 0.f); x4.w = fmaxf(x4.w, 0.f);
            }
            acc[i][0] += x4.x * w0.x + x4.y * w1.x + x4.z * w2.x + x4.w * w3.x;
            acc[i][1] += x4.x * w0.y + x4.y * w1.y + x4.z * w2.y + x4.w * w3.y;
            acc[i][2] += x4.x * w0.z + x4.y * w1.z + x4.z * w2.z + x4.w * w3.z;
            acc[i][3] += x4.x * w0.w + x4.y * w1.w + x4.z * w2.w + x4.w * w3.w;
        }
    }

#pragma unroll
    for (int i = 0; i < 4; ++i) {
        if (!rv[i]) continue;
        long long r = r0 + i;
#pragma unroll
        for (int j = 0; j < 4; ++j) {
            int c = txc * 4 + j;
            if (c < F) {
                int ch = c / CHW;
                int off = c - ch * CHW;
                Hc[(size_t)ch * n * CHW + r * CHW + off] = acc[i][j];
            }
        }
    }
}

// thread-per-row GEMV for tiny F (layer 3: K=50, F=6), row-major output.
template <int K, int F, bool RELU_IN>
__global__ __launch_bounds__(256) void gemv_rows_kernel(const float* __restrict__ X,
                                                        const float* __restrict__ W,
                                                        float* __restrict__ H, int n) {
    static_assert(K % 2 == 0, "K must be even");
    __shared__ float Ws[K * F];
    const int tid = threadIdx.x;
    for (int i = tid; i < K * F; i += 256) Ws[i] = W[i];
    __syncthreads();
    int r = blockIdx.x * 256 + tid;
    if (r >= n) return;
    float acc[F] = {};
    const float* xp = X + (long long)r * K;
    for (int k = 0; k < K; k += 2) {
        float2 x2 = *reinterpret_cast<const float2*>(xp + k);
        if (RELU_IN) { x2.x = fmaxf(x2.x, 0.f); x2.y = fmaxf(x2.y, 0.f); }
#pragma unroll
        for (int j = 0; j < F; ++j)
            acc[j] += x2.x * Ws[k * F + j] + x2.y * Ws[(k + 1) * F + j];
    }
    long long base = (long long)r * F;
#pragma unroll
    for (int j = 0; j < F; ++j) H[base + j] = acc[j];
}

// ---------------- NCH-chunk XCD-pinned CSR aggregation, float2 lanes ---------
// grid.x = NCH * ceil(n/NPB); chunk = blockIdx.x & (NCH-1). Lane l of a
// TPN-segment covers features [chunk*CHW + 2l, +1] via one float2 gather.
// Edge metadata via same-address broadcast loads; 8-deep unrolled.
template <int F, int CHW, int TPN, int NCH>
__global__ __launch_bounds__(BT) void agg_f2_kernel(const int* __restrict__ rowptr,
                                                    const long long* __restrict__ epack,
                                                    const float* __restrict__ H,
                                                    const float* __restrict__ dis,
                                                    const float* __restrict__ bias,
                                                    float* __restrict__ A, int n) {
    static_assert(CHW % 2 == 0, "CHW must be even");
    static_assert((NCH & (NCH - 1)) == 0, "NCH must be pow2");
    constexpr int NPB = BT / TPN;  // nodes per block
    constexpr int CH2 = CHW / 2;   // float2 per node per chunk
    const int chunk = blockIdx.x & (NCH - 1);
    const int nblk = blockIdx.x / NCH;
    const int tid = threadIdx.x;
    const int node = nblk * NPB + tid / TPN;
    const int lane = tid & (TPN - 1);
    if (node >= n) return;
    const float2* __restrict__ Hc = (const float2*)(H + (size_t)chunk * n * CHW);
    const int f = chunk * CHW + 2 * lane;
    const bool fv = (lane < CH2);

    float ax = 0.f, ay = 0.f;
    int j = rowptr[node];
    const int end = rowptr[node + 1];
    for (; j + 8 <= end; j += 8) {
        long long e0 = epack[j + 0];
        long long e1 = epack[j + 1];
        long long e2 = epack[j + 2];
        long long e3 = epack[j + 3];
        long long e4 = epack[j + 4];
        long long e5 = epack[j + 5];
        long long e6 = epack[j + 6];
        long long e7 = epack[j + 7];
        if (fv) {
            float2 h0 = Hc[(size_t)(int)e0 * CH2 + lane];
            float2 h1 = Hc[(size_t)(int)e1 * CH2 + lane];
            float2 h2 = Hc[(size_t)(int)e2 * CH2 + lane];
            float2 h3 = Hc[(size_t)(int)e3 * CH2 + lane];
            float2 h4 = Hc[(size_t)(int)e4 * CH2 + lane];
            float2 h5 = Hc[(size_t)(int)e5 * CH2 + lane];
            float2 h6 = Hc[(size_t)(int)e6 * CH2 + lane];
            float2 h7 = Hc[(size_t)(int)e7 * CH2 + lane];
            float n0 = __int_as_float((int)(e0 >> 32));
            float n1 = __int_as_float((int)(e1 >> 32));
            float n2 = __int_as_float((int)(e2 >> 32));
            float n3 = __int_as_float((int)(e3 >> 32));
            float n4 = __int_as_float((int)(e4 >> 32));
            float n5 = __int_as_float((int)(e5 >> 32));
            float n6 = __int_as_float((int)(e6 >> 32));
            float n7 = __int_as_float((int)(e7 >> 32));
            ax += n0 * h0.x; ay += n0 * h0.y;
            ax += n1 * h1.x; ay += n1 * h1.y;
            ax += n2 * h2.x; ay += n2 * h2.y;
            ax += n3 * h3.x; ay += n3 * h3.y;
            ax += n4 * h4.x; ay += n4 * h4.y;
            ax += n5 * h5.x; ay += n5 * h5.y;
            ax += n6 * h6.x; ay += n6 * h6.y;
            ax += n7 * h7.x; ay += n7 * h7.y;
        }
    }
    for (; j < end; ++j) {
        long long ev = epack[j];
        if (fv) {
            float2 h = Hc[(size_t)(int)ev * CH2 + lane];
            float nv = __int_as_float((int)(ev >> 32));
            ax += nv * h.x; ay += nv * h.y;
        }
    }
    if (fv) {
        float d = dis[node];
        float d2 = d * d;
        float2 hs = Hc[(size_t)node * CH2 + lane];
        if (f < F) {
            float v = bias[f] + d2 * hs.x + ax;
            __builtin_nontemporal_store(v, &A[(size_t)node * F + f]);
        }
        if (f + 1 < F) {
            float v = bias[f + 1] + d2 * hs.y + ay;
            __builtin_nontemporal_store(v, &A[(size_t)node * F + f + 1]);
        }
    }
}

// simple per-node agg for tiny F (row-major H, fully cache-resident)
template <int F, int TPN>
__global__ __launch_bounds__(BT) void agg_small_kernel(const int* __restrict__ rowptr,
                                                       const long long* __restrict__ epack,
                                                       const float* __restrict__ H,
                                                       const float* __restrict__ dis,
                                                       const float* __restrict__ bias,
                                                       float* __restrict__ A, int n) {
    int gid = blockIdx.x * blockDim.x + threadIdx.x;
    int node = gid / TPN;
    int lane = threadIdx.x & (TPN - 1);
    if (node >= n) return;
    bool active = (lane < F);
    float acc = 0.f;
    int j = rowptr[node];
    const int end = rowptr[node + 1];
    for (; j + 4 <= end; j += 4) {
        long long e0 = epack[j + 0];
        long long e1 = epack[j + 1];
        long long e2 = epack[j + 2];
        long long e3 = epack[j + 3];
        if (active) {
            float h0 = H[(size_t)(int)e0 * F + lane];
            float h1 = H[(size_t)(int)e1 * F + lane];
            float h2 = H[(size_t)(int)e2 * F + lane];
            float h3 = H[(size_t)(int)e3 * F + lane];
            acc += __int_as_float((int)(e0 >> 32)) * h0;
            acc += __int_as_float((int)(e1 >> 32)) * h1;
            acc += __int_as_float((int)(e2 >> 32)) * h2;
            acc += __int_as_float((int)(e3 >> 32)) * h3;
        }
    }
    for (; j < end; ++j) {
        long long ev = epack[j];
        if (active) acc += __int_as_float((int)(ev >> 32)) * H[(size_t)(int)ev * F + lane];
    }
    if (active) {
        float d = dis[node];
        float v = bias[lane] + d * d * H[(size_t)node * F + lane] + acc;
        __builtin_nontemporal_store(v, &A[(size_t)node * F + lane]);
    }
}

// ---------------------------------------------------------------------------
extern "C" void kernel_launch(void* const* d_in, const int* in_sizes, int n_in,
                              void* d_out, int out_size, void* d_ws, size_t ws_size,
                              hipStream_t stream) {
    const float* x  = (const float*)d_in[0];
    const int*   ei = (const int*)d_in[1];
    const float* ew = (const float*)d_in[2];
    const float* W0 = (const float*)d_in[3];
    const float* b0 = (const float*)d_in[4];
    const float* W1 = (const float*)d_in[5];
    const float* b1 = (const float*)d_in[6];
    const float* W2 = (const float*)d_in[7];
    const float* b2 = (const float*)d_in[8];
    const float* W3 = (const float*)d_in[9];
    const float* b3 = (const float*)d_in[10];
    float* out = (float*)d_out;

    const int N = in_sizes[0] / 128;  // 50000
    const int E = in_sizes[1] / 2;    // 800000
    const int* row = ei;
    const int* col = ei + E;

    const int NB = (N + SCAN_B - 1) / SCAN_B;

    // workspace (8B alignment maintained for epack):
    // dis[N] f | rowptr[N+2] i | cursor[N] i | bsums[SCAN_B] i |
    // epack[E] i64 | bufA[N*112] f (chunk-padded H, 8x14) | bufB[N*100] f
    // hist shadows (counts8[8N] i, wsum8[8N] f = 3.2MB) alias bufA (dead then).
    float* ws = (float*)d_ws;
    float* dis    = ws;
    int*   rowptr = (int*)(dis + N);
    int*   cursor = rowptr + (N + 2);
    int*   bsums  = cursor + N;
    long long* epack = (long long*)(bsums + SCAN_B);
    float* bufA   = (float*)(epack + E);
    float* bufB   = bufA + (size_t)N * 112;
    int*   counts8 = (int*)bufA;          // [8N]
    float* wsum8   = bufA + (size_t)8 * N;  // [8N]

    // ---- CSR + norm precompute ----
    zero8_kernel<<<(16 * N + BT - 1) / BT, BT, 0, stream>>>(bufA, 16 * N);
    hist8_kernel<<<(E + BT - 1) / BT, BT, 0, stream>>>(row, ew, counts8, wsum8, N, E);
    reduce8_kernel<<<(N + BT - 1) / BT, BT, 0, stream>>>(counts8, wsum8, rowptr, dis, N);
    scan1_kernel<<<NB, SCAN_B, 0, stream>>>(rowptr, bsums, dis, N);
    scan2_kernel<<<1, SCAN_B, 0, stream>>>(bsums, NB);
    scan3_kernel<<<(N + BT - 1) / BT, BT, 0, stream>>>(rowptr, bsums, cursor, N, E);
    fill_kernel<<<(E + BT - 1) / BT, BT, 0, stream>>>(row, col, ew, dis, cursor, epack, E);

    // GEMM rows/block: F=100 -> NCG=25, ROWS=40; F=50 -> NCG=13, ROWS=76
    const int g100_blocks = (N + 39) / 40;
    const int g50_blocks  = (N + 75) / 76;

    // agg grids: F=100: 8 chunks, CHW=14 (2.8MB slice), TPN=8, NPB=32;
    //            F=50:  4 chunks, CHW=14 (2.8MB slice), TPN=8, NPB=32.
    const int agg100_blocks = 8 * ((N + 31) / 32);
    const int agg50_blocks  = 4 * ((N + 31) / 32);
    const int agg6_blocks   = (N * 8 + BT - 1) / BT;

    // ---- layer 0: x(128) -> 100 ----
    gemm_tile_kernel<128, 100, 14, false><<<g100_blocks, 256, 0, stream>>>(x, W0, bufA, N);
    agg_f2_kernel<100, 14, 8, 8><<<agg100_blocks, BT, 0, stream>>>(rowptr, epack, bufA, dis, b0, bufB, N);

    // ---- layer 1: 100 -> 100 ----
    gemm_tile_kernel<100, 100, 14, true><<<g100_blocks, 256, 0, stream>>>(bufB, W1, bufA, N);
    agg_f2_kernel<100, 14, 8, 8><<<agg100_blocks, BT, 0, stream>>>(rowptr, epack, bufA, dis, b1, bufB, N);

    // ---- layer 2: 100 -> 50 ----
    gemm_tile_kernel<100, 50, 14, true><<<g50_blocks, 256, 0, stream>>>(bufB, W2, bufA, N);
    agg_f2_kernel<50, 14, 8, 4><<<agg50_blocks, BT, 0, stream>>>(rowptr, epack, bufA, dis, b2, bufB, N);

    // ---- layer 3: 50 -> 6 ----
    gemv_rows_kernel<50, 6, true><<<(N + 255) / 256, 256, 0, stream>>>(bufB, W3, bufA, N);
    agg_small_kernel<6, 8><<<agg6_blocks, BT, 0, stream>>>(rowptr, epack, bufA, dis, b3, out, N);
}

// Round 9
// 472.703 us; speedup vs baseline: 1.1690x; 1.1690x over previous
//
#include <hip/hip_runtime.h>

// ---------------------------------------------------------------------------
// GCN forward. Key evidence-driven design (R4-R8):
//  - agg cost ~ distinct cache lines gathered (VMEM addr-divergence serialization),
//    NOT bytes/hit-rate. So: H stored bf16, chunked CHW=32 = exactly ONE 64B
//    line per edge-chunk, line-aligned, 16 lanes x ushort2 all active.
//    F=100: NCH=4 (3.2MB slice, L2-resident, chunk=blockIdx&3 XCD-pinned);
//    F=50: NCH=2. Gathered-line count: 3.2M / 1.6M (R7 best was 6.4M).
//  - cross-XCD atomic ping-pong killed via 8 XCD-local shadows for BOTH
//    histogram (R8) and CSR-fill cursor (new): shadow = blockIdx & 7.
//  - edge (col,norm) packed i64, broadcast-loaded; A-stores nontemporal.
//  - messages quantized to bf16 (norm~0.06 scales rounding down); A/GEMM fp32.
// ---------------------------------------------------------------------------

#define BT 256
#define SCAN_B 256

__device__ inline float bf_lo(unsigned int v) { return __uint_as_float(v << 16); }
__device__ inline float bf_hi(unsigned int v) { return __uint_as_float(v & 0xFFFF0000u); }
__device__ inline unsigned short f2bf(float f) {  // round-to-nearest-even
    unsigned int u = __float_as_uint(f);
    unsigned int r = u + 0x7FFFu + ((u >> 16) & 1u);
    return (unsigned short)(r >> 16);
}

// ---------------- shadowed histogram ----------------
__global__ void zero8_kernel(float* buf, int n16) {  // counts8+wsum8 = 16N elems
    int i = blockIdx.x * blockDim.x + threadIdx.x;
    if (i < n16) buf[i] = 0.f;
}

__global__ void hist8_kernel(const int* __restrict__ row, const float* __restrict__ w,
                             int* counts8, float* wsum8, int n, int e) {
    int i = blockIdx.x * blockDim.x + threadIdx.x;
    if (i >= e) return;
    int s = blockIdx.x & 7;  // shadow pinned to one XCD under round-robin dispatch
    int r = row[i];
    atomicAdd(&counts8[s * n + r], 1);
    unsafeAtomicAdd(&wsum8[s * n + r], w[i]);
}

__global__ void reduce8_kernel(const int* __restrict__ counts8, const float* __restrict__ wsum8,
                               int* __restrict__ counts, float* __restrict__ deg, int n) {
    int i = blockIdx.x * blockDim.x + threadIdx.x;
    if (i >= n) return;
    int c = 0;
    float ws = 1.0f;  // self-loop weight
#pragma unroll
    for (int s = 0; s < 8; ++s) {
        c += counts8[s * n + i];
        ws += wsum8[s * n + i];
    }
    counts[i] = c;
    deg[i] = ws;
}

// exclusive scan of counts (in rowptr[0..n-1]); also deg -> dis in-place
__global__ void scan1_kernel(int* counts, int* bsums, float* deg, int n) {
    __shared__ int s[SCAN_B];
    int t = threadIdx.x;
    int i = blockIdx.x * SCAN_B + t;
    int v = (i < n) ? counts[i] : 0;
    s[t] = v;
    __syncthreads();
    for (int off = 1; off < SCAN_B; off <<= 1) {
        int x = (t >= off) ? s[t - off] : 0;
        __syncthreads();
        s[t] += x;
        __syncthreads();
    }
    if (i < n) {
        counts[i] = s[t] - v;  // exclusive
        float d = deg[i];
        deg[i] = (d > 0.f) ? rsqrtf(fmaxf(d, 1e-12f)) : 0.f;
    }
    if (t == SCAN_B - 1) bsums[blockIdx.x] = s[t];
}

__global__ void scan2_kernel(int* bsums, int nb) {  // single block, nb <= SCAN_B
    __shared__ int s[SCAN_B];
    int t = threadIdx.x;
    int v = (t < nb) ? bsums[t] : 0;
    s[t] = v;
    __syncthreads();
    for (int off = 1; off < SCAN_B; off <<= 1) {
        int x = (t >= off) ? s[t - off] : 0;
        __syncthreads();
        s[t] += x;
        __syncthreads();
    }
    if (t < nb) bsums[t] = s[t] - v;
}

// finalize rowptr; init 8 shadow cursors (cursor8[s][i] = rowptr[i] + sum_{t<s} counts8[t][i])
__global__ void scan3_kernel(int* rowptr, const int* __restrict__ bsums,
                             const int* __restrict__ counts8, int* __restrict__ cursor8,
                             int n, int e) {
    int i = blockIdx.x * blockDim.x + threadIdx.x;
    if (i < n) {
        int rp = rowptr[i] + bsums[i / SCAN_B];
        rowptr[i] = rp;
        int base = rp;
#pragma unroll
        for (int s = 0; s < 8; ++s) {
            cursor8[s * n + i] = base;
            base += counts8[s * n + i];
        }
    }
    if (i == 0) rowptr[n] = e;
}

// fill CSR; shadow cursor = XCD-local atomics (same block->shadow map as hist8)
__global__ void fill_kernel(const int* __restrict__ row, const int* __restrict__ col,
                            const float* __restrict__ w, const float* __restrict__ dis,
                            int* cursor8, long long* __restrict__ epack, int n, int e) {
    int i = blockIdx.x * blockDim.x + threadIdx.x;
    if (i >= e) return;
    int s = blockIdx.x & 7;
    int r = row[i], c = col[i];
    float nv = dis[r] * w[i] * dis[c];
    int dst = atomicAdd(&cursor8[s * n + r], 1);
    long long v = ((long long)__float_as_int(nv) << 32) | (unsigned int)c;
    __builtin_nontemporal_store(v, &epack[dst]);
}

// ---------------- register-tiled GEMM: Hc(bf16) = chunked(actin(X) @ W) ------
// X row-major fp32 [n,K] (K%4==0); output bf16 chunked Hc[c/32][n][c%32],
// 32 bf16 = 64B = one cache line per node per chunk.
template <int K, int F, bool RELU_IN>
__global__ __launch_bounds__(256) void gemm_bf16_kernel(const float* __restrict__ X,
                                                        const float* __restrict__ W,
                                                        unsigned short* __restrict__ Hc, int n) {
    static_assert(K % 4 == 0, "K must be multiple of 4");
    constexpr int NCG = (F + 3) / 4;
    constexpr int FP = NCG * 4;
    constexpr int RG = 256 / NCG;
    constexpr int ROWS = RG * 4;

    __shared__ float Ws[K * FP];
    const int tid = threadIdx.x;
    for (int i = tid; i < K * FP; i += 256) {
        int k = i / FP, c = i - k * FP;
        Ws[i] = (c < F) ? W[k * F + c] : 0.f;  // zero-pad -> pad cols store 0
    }
    __syncthreads();

    const int txc = tid % NCG;
    const int tyr = tid / NCG;
    if (tyr >= RG) return;

    const int r0 = blockIdx.x * ROWS + tyr * 4;
    bool rv[4];
    const float* xrow[4];
#pragma unroll
    for (int i = 0; i < 4; ++i) {
        int r = r0 + i;
        rv[i] = (r < n);
        xrow[i] = X + (long long)(rv[i] ? r : 0) * K;
    }

    float acc[4][4] = {};
    const float* wbase = &Ws[txc * 4];
    for (int k = 0; k < K; k += 4) {
        float4 w0 = *reinterpret_cast<const float4*>(wbase + (k + 0) * FP);
        float4 w1 = *reinterpret_cast<const float4*>(wbase + (k + 1) * FP);
        float4 w2 = *reinterpret_cast<const float4*>(wbase + (k + 2) * FP);
        float4 w3 = *reinterpret_cast<const float4*>(wbase + (k + 3) * FP);
#pragma unroll
        for (int i = 0; i < 4; ++i) {
            float4 x4 = *reinterpret_cast<const float4*>(xrow[i] + k);
            if (RELU_IN) {
                x4.x = fmaxf(x4.x, 0.f); x4.y = fmaxf(x4.y, 0.f);
                x4.z = fmaxf(x4.z, 0.f); x4.w = fmaxf(x4.w, 0.f);
            }
            acc[i][0] += x4.x * w0.x + x4.y * w1.x + x4.z * w2.x + x4.w * w3.x;
            acc[i][1] += x4.x * w0.y + x4.y * w1.y + x4.z * w2.y + x4.w * w3.y;
            acc[i][2] += x4.x * w0.z + x4.y * w1.z + x4.z * w2.z + x4.w * w3.z;
            acc[i][3] += x4.x * w0.w + x4.y * w1.w + x4.z * w2.w + x4.w * w3.w;
        }
    }

    // 4-col group is contiguous and 4-aligned -> fits one chunk; 8B store.
    const int c0 = txc * 4;
    const int ch = c0 >> 5;
    const int off = c0 & 31;
#pragma unroll
    for (int i = 0; i < 4; ++i) {
        if (!rv[i]) continue;
        ushort4 pk;
        pk.x = f2bf(acc[i][0]); pk.y = f2bf(acc[i][1]);
        pk.z = f2bf(acc[i][2]); pk.w = f2bf(acc[i][3]);
        *reinterpret_cast<ushort4*>(&Hc[(size_t)ch * n * 32 + (size_t)(r0 + i) * 32 + off]) = pk;
    }
}

// thread-per-row GEMV for tiny F (layer 3: K=50, F=6), fp32 row-major output.
template <int K, int F, bool RELU_IN>
__global__ __launch_bounds__(256) void gemv_rows_kernel(const float* __restrict__ X,
                                                        const float* __restrict__ W,
                                                        float* __restrict__ H, int n) {
    static_assert(K % 2 == 0, "K must be even");
    __shared__ float Ws[K * F];
    const int tid = threadIdx.x;
    for (int i = tid; i < K * F; i += 256) Ws[i] = W[i];
    __syncthreads();
    int r = blockIdx.x * 256 + tid;
    if (r >= n) return;
    float acc[F] = {};
    const float* xp = X + (long long)r * K;
    for (int k = 0; k < K; k += 2) {
        float2 x2 = *reinterpret_cast<const float2*>(xp + k);
        if (RELU_IN) { x2.x = fmaxf(x2.x, 0.f); x2.y = fmaxf(x2.y, 0.f); }
#pragma unroll
        for (int j = 0; j < F; ++j)
            acc[j] += x2.x * Ws[k * F + j] + x2.y * Ws[(k + 1) * F + j];
    }
    long long base = (long long)r * F;
#pragma unroll
    for (int j = 0; j < F; ++j) H[base + j] = acc[j];
}

// ---------------- bf16 chunked CSR aggregation ----------------
// grid.x = NCH * ceil(n/16); chunk = blockIdx.x & (NCH-1) (XCD-pinned).
// TPN=16 lanes, lane loads ushort2 (uint) -> one 64B line per edge-chunk,
// all lanes active. Edge metadata same-address broadcast; 8-deep unrolled.
template <int F, int NCH>
__global__ __launch_bounds__(BT) void agg_bf16_kernel(const int* __restrict__ rowptr,
                                                      const long long* __restrict__ epack,
                                                      const unsigned int* __restrict__ H,
                                                      const float* __restrict__ dis,
                                                      const float* __restrict__ bias,
                                                      float* __restrict__ A, int n) {
    constexpr int TPN = 16, NPB = BT / TPN;
    const int chunk = blockIdx.x & (NCH - 1);
    const int nblk = blockIdx.x / NCH;
    const int node = nblk * NPB + threadIdx.x / TPN;
    const int lane = threadIdx.x & (TPN - 1);
    if (node >= n) return;
    const unsigned int* __restrict__ Hc = H + (size_t)chunk * n * 16;  // 16 uints = 64B/node
    const int f = chunk * 32 + 2 * lane;

    float ax = 0.f, ay = 0.f;
    int j = rowptr[node];
    const int end = rowptr[node + 1];
    for (; j + 8 <= end; j += 8) {
        long long e0 = epack[j + 0];
        long long e1 = epack[j + 1];
        long long e2 = epack[j + 2];
        long long e3 = epack[j + 3];
        long long e4 = epack[j + 4];
        long long e5 = epack[j + 5];
        long long e6 = epack[j + 6];
        long long e7 = epack[j + 7];
        unsigned int v0 = Hc[(size_t)(int)e0 * 16 + lane];
        unsigned int v1 = Hc[(size_t)(int)e1 * 16 + lane];
        unsigned int v2 = Hc[(size_t)(int)e2 * 16 + lane];
        unsigned int v3 = Hc[(size_t)(int)e3 * 16 + lane];
        unsigned int v4 = Hc[(size_t)(int)e4 * 16 + lane];
        unsigned int v5 = Hc[(size_t)(int)e5 * 16 + lane];
        unsigned int v6 = Hc[(size_t)(int)e6 * 16 + lane];
        unsigned int v7 = Hc[(size_t)(int)e7 * 16 + lane];
        float n0 = __int_as_float((int)(e0 >> 32));
        float n1 = __int_as_float((int)(e1 >> 32));
        float n2 = __int_as_float((int)(e2 >> 32));
        float n3 = __int_as_float((int)(e3 >> 32));
        float n4 = __int_as_float((int)(e4 >> 32));
        float n5 = __int_as_float((int)(e5 >> 32));
        float n6 = __int_as_float((int)(e6 >> 32));
        float n7 = __int_as_float((int)(e7 >> 32));
        ax += n0 * bf_lo(v0); ay += n0 * bf_hi(v0);
        ax += n1 * bf_lo(v1); ay += n1 * bf_hi(v1);
        ax += n2 * bf_lo(v2); ay += n2 * bf_hi(v2);
        ax += n3 * bf_lo(v3); ay += n3 * bf_hi(v3);
        ax += n4 * bf_lo(v4); ay += n4 * bf_hi(v4);
        ax += n5 * bf_lo(v5); ay += n5 * bf_hi(v5);
        ax += n6 * bf_lo(v6); ay += n6 * bf_hi(v6);
        ax += n7 * bf_lo(v7); ay += n7 * bf_hi(v7);
    }
    for (; j < end; ++j) {
        long long ev = epack[j];
        unsigned int v = Hc[(size_t)(int)ev * 16 + lane];
        float nv = __int_as_float((int)(ev >> 32));
        ax += nv * bf_lo(v); ay += nv * bf_hi(v);
    }
    float d = dis[node];
    float d2 = d * d;
    unsigned int hs = Hc[(size_t)node * 16 + lane];
    if (f < F) {
        float v = bias[f] + d2 * bf_lo(hs) + ax;
        __builtin_nontemporal_store(v, &A[(size_t)node * F + f]);
    }
    if (f + 1 < F) {
        float v = bias[f + 1] + d2 * bf_hi(hs) + ay;
        __builtin_nontemporal_store(v, &A[(size_t)node * F + f + 1]);
    }
}

// simple per-node agg for tiny F (fp32 row-major H, fully cache-resident)
template <int F, int TPN>
__global__ __launch_bounds__(BT) void agg_small_kernel(const int* __restrict__ rowptr,
                                                       const long long* __restrict__ epack,
                                                       const float* __restrict__ H,
                                                       const float* __restrict__ dis,
                                                       const float* __restrict__ bias,
                                                       float* __restrict__ A, int n) {
    int gid = blockIdx.x * blockDim.x + threadIdx.x;
    int node = gid / TPN;
    int lane = threadIdx.x & (TPN - 1);
    if (node >= n) return;
    bool active = (lane < F);
    float acc = 0.f;
    int j = rowptr[node];
    const int end = rowptr[node + 1];
    for (; j + 4 <= end; j += 4) {
        long long e0 = epack[j + 0];
        long long e1 = epack[j + 1];
        long long e2 = epack[j + 2];
        long long e3 = epack[j + 3];
        if (active) {
            float h0 = H[(size_t)(int)e0 * F + lane];
            float h1 = H[(size_t)(int)e1 * F + lane];
            float h2 = H[(size_t)(int)e2 * F + lane];
            float h3 = H[(size_t)(int)e3 * F + lane];
            acc += __int_as_float((int)(e0 >> 32)) * h0;
            acc += __int_as_float((int)(e1 >> 32)) * h1;
            acc += __int_as_float((int)(e2 >> 32)) * h2;
            acc += __int_as_float((int)(e3 >> 32)) * h3;
        }
    }
    for (; j < end; ++j) {
        long long ev = epack[j];
        if (active) acc += __int_as_float((int)(ev >> 32)) * H[(size_t)(int)ev * F + lane];
    }
    if (active) {
        float d = dis[node];
        float v = bias[lane] + d * d * H[(size_t)node * F + lane] + acc;
        __builtin_nontemporal_store(v, &A[(size_t)node * F + lane]);
    }
}

// ---------------------------------------------------------------------------
extern "C" void kernel_launch(void* const* d_in, const int* in_sizes, int n_in,
                              void* d_out, int out_size, void* d_ws, size_t ws_size,
                              hipStream_t stream) {
    const float* x  = (const float*)d_in[0];
    const int*   ei = (const int*)d_in[1];
    const float* ew = (const float*)d_in[2];
    const float* W0 = (const float*)d_in[3];
    const float* b0 = (const float*)d_in[4];
    const float* W1 = (const float*)d_in[5];
    const float* b1 = (const float*)d_in[6];
    const float* W2 = (const float*)d_in[7];
    const float* b2 = (const float*)d_in[8];
    const float* W3 = (const float*)d_in[9];
    const float* b3 = (const float*)d_in[10];
    float* out = (float*)d_out;

    const int N = in_sizes[0] / 128;  // 50000
    const int E = in_sizes[1] / 2;    // 800000
    const int* row = ei;
    const int* col = ei + E;

    const int NB = (N + SCAN_B - 1) / SCAN_B;

    // workspace, 64B-aligned sections:
    // dis[N] f | rowptr[N+2] i | bsums[SCAN_B] i | epack[E] i64 |
    // bufA: 128N bf16 (chunked H, 64B rows); pre-CSR aliases counts8[8N] i + wsum8[8N] f;
    //       layer-3 aliases H3[6N] f
    // bufB: 100N f (A, row-major); pre-CSR aliases cursor8[8N] i
    char* p = (char*)d_ws;
    auto alloc = [&](size_t bytes) {
        p = (char*)(((uintptr_t)p + 63) & ~(uintptr_t)63);
        void* r = (void*)p;
        p += bytes;
        return r;
    };
    float* dis    = (float*)alloc((size_t)N * 4);
    int*   rowptr = (int*)alloc((size_t)(N + 2) * 4);
    int*   bsums  = (int*)alloc(SCAN_B * 4);
    long long* epack = (long long*)alloc((size_t)E * 8);
    unsigned short* bufA = (unsigned short*)alloc((size_t)N * 128 * 2);
    float* bufB   = (float*)alloc((size_t)N * 100 * 4);

    int*   counts8 = (int*)bufA;                 // [8N]
    float* wsum8   = (float*)bufA + 8 * (size_t)N;  // [8N]
    int*   cursor8 = (int*)bufB;                 // [8N]
    float* bufAf   = (float*)bufA;               // layer-3 fp32 H3[N,6]

    // ---- CSR + norm precompute ----
    zero8_kernel<<<(16 * N + BT - 1) / BT, BT, 0, stream>>>((float*)bufA, 16 * N);
    hist8_kernel<<<(E + BT - 1) / BT, BT, 0, stream>>>(row, ew, counts8, wsum8, N, E);
    reduce8_kernel<<<(N + BT - 1) / BT, BT, 0, stream>>>(counts8, wsum8, rowptr, dis, N);
    scan1_kernel<<<NB, SCAN_B, 0, stream>>>(rowptr, bsums, dis, N);
    scan2_kernel<<<1, SCAN_B, 0, stream>>>(bsums, NB);
    scan3_kernel<<<(N + BT - 1) / BT, BT, 0, stream>>>(rowptr, bsums, counts8, cursor8, N, E);
    fill_kernel<<<(E + BT - 1) / BT, BT, 0, stream>>>(row, col, ew, dis, cursor8, epack, N, E);

    // GEMM rows/block: F=100 -> NCG=25, ROWS=40; F=50 -> NCG=13, ROWS=76
    const int g100_blocks = (N + 39) / 40;
    const int g50_blocks  = (N + 75) / 76;

    const int agg100_blocks = 4 * ((N + 15) / 16);  // NCH=4
    const int agg50_blocks  = 2 * ((N + 15) / 16);  // NCH=2
    const int agg6_blocks   = (N * 8 + BT - 1) / BT;

    // ---- layer 0: x(128) -> 100 ----
    gemm_bf16_kernel<128, 100, false><<<g100_blocks, 256, 0, stream>>>(x, W0, bufA, N);
    agg_bf16_kernel<100, 4><<<agg100_blocks, BT, 0, stream>>>(rowptr, epack, (const unsigned int*)bufA, dis, b0, bufB, N);

    // ---- layer 1: 100 -> 100 ----
    gemm_bf16_kernel<100, 100, true><<<g100_blocks, 256, 0, stream>>>(bufB, W1, bufA, N);
    agg_bf16_kernel<100, 4><<<agg100_blocks, BT, 0, stream>>>(rowptr, epack, (const unsigned int*)bufA, dis, b1, bufB, N);

    // ---- layer 2: 100 -> 50 ----
    gemm_bf16_kernel<100, 50, true><<<g50_blocks, 256, 0, stream>>>(bufB, W2, bufA, N);
    agg_bf16_kernel<50, 2><<<agg50_blocks, BT, 0, stream>>>(rowptr, epack, (const unsigned int*)bufA, dis, b2, bufB, N);

    // ---- layer 3: 50 -> 6 ----
    gemv_rows_kernel<50, 6, true><<<(N + 255) / 256, 256, 0, stream>>>(bufB, W3, bufAf, N);
    agg_small_kernel<6, 8><<<agg6_blocks, BT, 0, stream>>>(rowptr, epack, bufAf, dis, b3, out, N);
}

// Round 10
// 418.338 us; speedup vs baseline: 1.3209x; 1.1300x over previous
//
#include <hip/hip_runtime.h>

// ---------------------------------------------------------------------------
// GCN forward. Evidence-driven design (R4-R10):
//  - agg cost ~ distinct cache lines gathered: H stored bf16, chunked CHW=32
//    = ONE 64B line per edge-chunk, 16 lanes x ushort2. F=100: NCH=4 chunks
//    (3.2MB XCD-pinned L2-resident slice); F=50: NCH=2. (R9: 552->472)
//  - device-scope atomics execute memory-side (R9: WRITE=E*64B at 710GB/s);
//    shadowing can't localize them. So: ONE 32-bit packed atomic per edge,
//    val=(1<<24)|round(w*2^16) -> count in [24:32), wsum fixed-point in [0:24).
//    Returned old>>24 = per-row rank -> CSR fill is ATOMIC-FREE:
//    slot = rowptr[r] + rank[i].
//  - edge (col,norm) packed i64, broadcast-loaded; A-stores nontemporal.
// ---------------------------------------------------------------------------

#define BT 256
#define SCAN_B 256

__device__ inline float bf_lo(unsigned int v) { return __uint_as_float(v << 16); }
__device__ inline float bf_hi(unsigned int v) { return __uint_as_float(v & 0xFFFF0000u); }
__device__ inline unsigned short f2bf(float f) {  // round-to-nearest-even
    unsigned int u = __float_as_uint(f);
    unsigned int r = u + 0x7FFFu + ((u >> 16) & 1u);
    return (unsigned short)(r >> 16);
}

// ---------------- precompute: packed histogram + rank ----------------
__global__ void zero_kernel(unsigned int* cw, int n) {
    int i = blockIdx.x * blockDim.x + threadIdx.x;
    if (i < n) cw[i] = 0u;
}

// cw[r] += (1<<24) | round(w*65536); rank[i] = old>>24 (unique ordinal in row r)
__global__ void hist_kernel(const int* __restrict__ row, const float* __restrict__ w,
                            unsigned int* cw, int* __restrict__ rank, int e) {
    int i = blockIdx.x * blockDim.x + threadIdx.x;
    if (i >= e) return;
    unsigned int wq = (unsigned int)(w[i] * 65536.0f + 0.5f);
    unsigned int old = atomicAdd(&cw[row[i]], (1u << 24) | wq);
    rank[i] = (int)(old >> 24);
}

// counts (from cw) -> exclusive scan into rowptr[0..n-1]; cw wsum -> dis
__global__ void scan1_kernel(const unsigned int* __restrict__ cw, int* rowptr,
                             int* bsums, float* dis, int n) {
    __shared__ int s[SCAN_B];
    int t = threadIdx.x;
    int i = blockIdx.x * SCAN_B + t;
    unsigned int cv = (i < n) ? cw[i] : 0u;
    int v = (int)(cv >> 24);
    s[t] = v;
    __syncthreads();
    for (int off = 1; off < SCAN_B; off <<= 1) {
        int x = (t >= off) ? s[t - off] : 0;
        __syncthreads();
        s[t] += x;
        __syncthreads();
    }
    if (i < n) {
        rowptr[i] = s[t] - v;  // exclusive (pre block-offset)
        float d = 1.0f + (float)(cv & 0xFFFFFFu) * (1.0f / 65536.0f);  // +self-loop
        dis[i] = rsqrtf(fmaxf(d, 1e-12f));
    }
    if (t == SCAN_B - 1) bsums[blockIdx.x] = s[t];
}

__global__ void scan2_kernel(int* bsums, int nb) {  // single block, nb <= SCAN_B
    __shared__ int s[SCAN_B];
    int t = threadIdx.x;
    int v = (t < nb) ? bsums[t] : 0;
    s[t] = v;
    __syncthreads();
    for (int off = 1; off < SCAN_B; off <<= 1) {
        int x = (t >= off) ? s[t - off] : 0;
        __syncthreads();
        s[t] += x;
        __syncthreads();
    }
    if (t < nb) bsums[t] = s[t] - v;
}

__global__ void scan3_kernel(int* rowptr, const int* __restrict__ bsums, int n, int e) {
    int i = blockIdx.x * blockDim.x + threadIdx.x;
    if (i < n) rowptr[i] += bsums[i / SCAN_B];
    if (i == 0) rowptr[n] = e;
}

// atomic-free CSR fill: slot = rowptr[r] + rank[i]
__global__ void fill_kernel(const int* __restrict__ row, const int* __restrict__ col,
                            const float* __restrict__ w, const float* __restrict__ dis,
                            const int* __restrict__ rowptr, const int* __restrict__ rank,
                            long long* __restrict__ epack, int e) {
    int i = blockIdx.x * blockDim.x + threadIdx.x;
    if (i >= e) return;
    int r = row[i], c = col[i];
    float nv = dis[r] * w[i] * dis[c];
    int dst = rowptr[r] + rank[i];
    long long v = ((long long)__float_as_int(nv) << 32) | (unsigned int)c;
    __builtin_nontemporal_store(v, &epack[dst]);
}

// ---------------- register-tiled GEMM: Hc(bf16) = chunked(actin(X) @ W) ------
// X row-major fp32 [n,K] (K%4==0); output bf16 chunked Hc[c/32][n][c%32],
// 32 bf16 = 64B = one cache line per node per chunk.
template <int K, int F, bool RELU_IN>
__global__ __launch_bounds__(256) void gemm_bf16_kernel(const float* __restrict__ X,
                                                        const float* __restrict__ W,
                                                        unsigned short* __restrict__ Hc, int n) {
    static_assert(K % 4 == 0, "K must be multiple of 4");
    constexpr int NCG = (F + 3) / 4;
    constexpr int FP = NCG * 4;
    constexpr int RG = 256 / NCG;
    constexpr int ROWS = RG * 4;

    __shared__ float Ws[K * FP];
    const int tid = threadIdx.x;
    for (int i = tid; i < K * FP; i += 256) {
        int k = i / FP, c = i - k * FP;
        Ws[i] = (c < F) ? W[k * F + c] : 0.f;  // zero-pad -> pad cols store 0
    }
    __syncthreads();

    const int txc = tid % NCG;
    const int tyr = tid / NCG;
    if (tyr >= RG) return;

    const int r0 = blockIdx.x * ROWS + tyr * 4;
    bool rv[4];
    const float* xrow[4];
#pragma unroll
    for (int i = 0; i < 4; ++i) {
        int r = r0 + i;
        rv[i] = (r < n);
        xrow[i] = X + (long long)(rv[i] ? r : 0) * K;
    }

    float acc[4][4] = {};
    const float* wbase = &Ws[txc * 4];
    for (int k = 0; k < K; k += 4) {
        float4 w0 = *reinterpret_cast<const float4*>(wbase + (k + 0) * FP);
        float4 w1 = *reinterpret_cast<const float4*>(wbase + (k + 1) * FP);
        float4 w2 = *reinterpret_cast<const float4*>(wbase + (k + 2) * FP);
        float4 w3 = *reinterpret_cast<const float4*>(wbase + (k + 3) * FP);
#pragma unroll
        for (int i = 0; i < 4; ++i) {
            float4 x4 = *reinterpret_cast<const float4*>(xrow[i] + k);
            if (RELU_IN) {
                x4.x = fmaxf(x4.x, 0.f); x4.y = fmaxf(x4.y, 0.f);
                x4.z = fmaxf(x4.z, 0.f); x4.w = fmaxf(x4.w, 0.f);
            }
            acc[i][0] += x4.x * w0.x + x4.y * w1.x + x4.z * w2.x + x4.w * w3.x;
            acc[i][1] += x4.x * w0.y + x4.y * w1.y + x4.z * w2.y + x4.w * w3.y;
            acc[i][2] += x4.x * w0.z + x4.y * w1.z + x4.z * w2.z + x4.w * w3.z;
            acc[i][3] += x4.x * w0.w + x4.y * w1.w + x4.z * w2.w + x4.w * w3.w;
        }
    }

    // 4-col group is contiguous and 4-aligned -> fits one chunk; 8B store.
    const int c0 = txc * 4;
    const int ch = c0 >> 5;
    const int off = c0 & 31;
#pragma unroll
    for (int i = 0; i < 4; ++i) {
        if (!rv[i]) continue;
        ushort4 pk;
        pk.x = f2bf(acc[i][0]); pk.y = f2bf(acc[i][1]);
        pk.z = f2bf(acc[i][2]); pk.w = f2bf(acc[i][3]);
        *reinterpret_cast<ushort4*>(&Hc[(size_t)ch * n * 32 + (size_t)(r0 + i) * 32 + off]) = pk;
    }
}

// thread-per-row GEMV for tiny F (layer 3: K=50, F=6), fp32 row-major output.
template <int K, int F, bool RELU_IN>
__global__ __launch_bounds__(256) void gemv_rows_kernel(const float* __restrict__ X,
                                                        const float* __restrict__ W,
                                                        float* __restrict__ H, int n) {
    static_assert(K % 2 == 0, "K must be even");
    __shared__ float Ws[K * F];
    const int tid = threadIdx.x;
    for (int i = tid; i < K * F; i += 256) Ws[i] = W[i];
    __syncthreads();
    int r = blockIdx.x * 256 + tid;
    if (r >= n) return;
    float acc[F] = {};
    const float* xp = X + (long long)r * K;
    for (int k = 0; k < K; k += 2) {
        float2 x2 = *reinterpret_cast<const float2*>(xp + k);
        if (RELU_IN) { x2.x = fmaxf(x2.x, 0.f); x2.y = fmaxf(x2.y, 0.f); }
#pragma unroll
        for (int j = 0; j < F; ++j)
            acc[j] += x2.x * Ws[k * F + j] + x2.y * Ws[(k + 1) * F + j];
    }
    long long base = (long long)r * F;
#pragma unroll
    for (int j = 0; j < F; ++j) H[base + j] = acc[j];
}

// ---------------- bf16 chunked CSR aggregation ----------------
// grid.x = NCH * ceil(n/16); chunk = blockIdx.x & (NCH-1) (XCD-pinned).
// TPN=16 lanes, lane loads ushort2 (uint) -> one 64B line per edge-chunk,
// all lanes active. Edge metadata same-address broadcast; 8-deep unrolled.
template <int F, int NCH>
__global__ __launch_bounds__(BT) void agg_bf16_kernel(const int* __restrict__ rowptr,
                                                      const long long* __restrict__ epack,
                                                      const unsigned int* __restrict__ H,
                                                      const float* __restrict__ dis,
                                                      const float* __restrict__ bias,
                                                      float* __restrict__ A, int n) {
    constexpr int TPN = 16, NPB = BT / TPN;
    const int chunk = blockIdx.x & (NCH - 1);
    const int nblk = blockIdx.x / NCH;
    const int node = nblk * NPB + threadIdx.x / TPN;
    const int lane = threadIdx.x & (TPN - 1);
    if (node >= n) return;
    const unsigned int* __restrict__ Hc = H + (size_t)chunk * n * 16;  // 16 uints = 64B/node
    const int f = chunk * 32 + 2 * lane;

    float ax = 0.f, ay = 0.f;
    int j = rowptr[node];
    const int end = rowptr[node + 1];
    for (; j + 8 <= end; j += 8) {
        long long e0 = epack[j + 0];
        long long e1 = epack[j + 1];
        long long e2 = epack[j + 2];
        long long e3 = epack[j + 3];
        long long e4 = epack[j + 4];
        long long e5 = epack[j + 5];
        long long e6 = epack[j + 6];
        long long e7 = epack[j + 7];
        unsigned int v0 = Hc[(size_t)(int)e0 * 16 + lane];
        unsigned int v1 = Hc[(size_t)(int)e1 * 16 + lane];
        unsigned int v2 = Hc[(size_t)(int)e2 * 16 + lane];
        unsigned int v3 = Hc[(size_t)(int)e3 * 16 + lane];
        unsigned int v4 = Hc[(size_t)(int)e4 * 16 + lane];
        unsigned int v5 = Hc[(size_t)(int)e5 * 16 + lane];
        unsigned int v6 = Hc[(size_t)(int)e6 * 16 + lane];
        unsigned int v7 = Hc[(size_t)(int)e7 * 16 + lane];
        float n0 = __int_as_float((int)(e0 >> 32));
        float n1 = __int_as_float((int)(e1 >> 32));
        float n2 = __int_as_float((int)(e2 >> 32));
        float n3 = __int_as_float((int)(e3 >> 32));
        float n4 = __int_as_float((int)(e4 >> 32));
        float n5 = __int_as_float((int)(e5 >> 32));
        float n6 = __int_as_float((int)(e6 >> 32));
        float n7 = __int_as_float((int)(e7 >> 32));
        ax += n0 * bf_lo(v0); ay += n0 * bf_hi(v0);
        ax += n1 * bf_lo(v1); ay += n1 * bf_hi(v1);
        ax += n2 * bf_lo(v2); ay += n2 * bf_hi(v2);
        ax += n3 * bf_lo(v3); ay += n3 * bf_hi(v3);
        ax += n4 * bf_lo(v4); ay += n4 * bf_hi(v4);
        ax += n5 * bf_lo(v5); ay += n5 * bf_hi(v5);
        ax += n6 * bf_lo(v6); ay += n6 * bf_hi(v6);
        ax += n7 * bf_lo(v7); ay += n7 * bf_hi(v7);
    }
    for (; j < end; ++j) {
        long long ev = epack[j];
        unsigned int v = Hc[(size_t)(int)ev * 16 + lane];
        float nv = __int_as_float((int)(ev >> 32));
        ax += nv * bf_lo(v); ay += nv * bf_hi(v);
    }
    float d = dis[node];
    float d2 = d * d;
    unsigned int hs = Hc[(size_t)node * 16 + lane];
    if (f < F) {
        float v = bias[f] + d2 * bf_lo(hs) + ax;
        __builtin_nontemporal_store(v, &A[(size_t)node * F + f]);
    }
    if (f + 1 < F) {
        float v = bias[f + 1] + d2 * bf_hi(hs) + ay;
        __builtin_nontemporal_store(v, &A[(size_t)node * F + f + 1]);
    }
}

// simple per-node agg for tiny F (fp32 row-major H, fully cache-resident)
template <int F, int TPN>
__global__ __launch_bounds__(BT) void agg_small_kernel(const int* __restrict__ rowptr,
                                                       const long long* __restrict__ epack,
                                                       const float* __restrict__ H,
                                                       const float* __restrict__ dis,
                                                       const float* __restrict__ bias,
                                                       float* __restrict__ A, int n) {
    int gid = blockIdx.x * blockDim.x + threadIdx.x;
    int node = gid / TPN;
    int lane = threadIdx.x & (TPN - 1);
    if (node >= n) return;
    bool active = (lane < F);
    float acc = 0.f;
    int j = rowptr[node];
    const int end = rowptr[node + 1];
    for (; j + 4 <= end; j += 4) {
        long long e0 = epack[j + 0];
        long long e1 = epack[j + 1];
        long long e2 = epack[j + 2];
        long long e3 = epack[j + 3];
        if (active) {
            float h0 = H[(size_t)(int)e0 * F + lane];
            float h1 = H[(size_t)(int)e1 * F + lane];
            float h2 = H[(size_t)(int)e2 * F + lane];
            float h3 = H[(size_t)(int)e3 * F + lane];
            acc += __int_as_float((int)(e0 >> 32)) * h0;
            acc += __int_as_float((int)(e1 >> 32)) * h1;
            acc += __int_as_float((int)(e2 >> 32)) * h2;
            acc += __int_as_float((int)(e3 >> 32)) * h3;
        }
    }
    for (; j < end; ++j) {
        long long ev = epack[j];
        if (active) acc += __int_as_float((int)(ev >> 32)) * H[(size_t)(int)ev * F + lane];
    }
    if (active) {
        float d = dis[node];
        float v = bias[lane] + d * d * H[(size_t)node * F + lane] + acc;
        __builtin_nontemporal_store(v, &A[(size_t)node * F + lane]);
    }
}

// ---------------------------------------------------------------------------
extern "C" void kernel_launch(void* const* d_in, const int* in_sizes, int n_in,
                              void* d_out, int out_size, void* d_ws, size_t ws_size,
                              hipStream_t stream) {
    const float* x  = (const float*)d_in[0];
    const int*   ei = (const int*)d_in[1];
    const float* ew = (const float*)d_in[2];
    const float* W0 = (const float*)d_in[3];
    const float* b0 = (const float*)d_in[4];
    const float* W1 = (const float*)d_in[5];
    const float* b1 = (const float*)d_in[6];
    const float* W2 = (const float*)d_in[7];
    const float* b2 = (const float*)d_in[8];
    const float* W3 = (const float*)d_in[9];
    const float* b3 = (const float*)d_in[10];
    float* out = (float*)d_out;

    const int N = in_sizes[0] / 128;  // 50000
    const int E = in_sizes[1] / 2;    // 800000
    const int* row = ei;
    const int* col = ei + E;

    const int NB = (N + SCAN_B - 1) / SCAN_B;

    // workspace, 64B-aligned sections:
    // dis[N] f | rowptr[N+2] i | bsums i | cw[N] u32 | rank[E] i | epack[E] i64 |
    // bufA: 128N bf16 (chunked H, 64B rows; layer-3 aliases fp32 H3[6N]) |
    // bufB: 100N f (A, row-major)
    char* p = (char*)d_ws;
    auto alloc = [&](size_t bytes) {
        p = (char*)(((uintptr_t)p + 63) & ~(uintptr_t)63);
        void* r = (void*)p;
        p += bytes;
        return r;
    };
    float* dis    = (float*)alloc((size_t)N * 4);
    int*   rowptr = (int*)alloc((size_t)(N + 2) * 4);
    int*   bsums  = (int*)alloc(SCAN_B * 4);
    unsigned int* cw = (unsigned int*)alloc((size_t)N * 4);
    int*   rank   = (int*)alloc((size_t)E * 4);
    long long* epack = (long long*)alloc((size_t)E * 8);
    unsigned short* bufA = (unsigned short*)alloc((size_t)N * 128 * 2);
    float* bufB   = (float*)alloc((size_t)N * 100 * 4);
    float* bufAf  = (float*)bufA;  // layer-3 fp32 H3[N,6]

    // ---- CSR + norm precompute (one 32-bit atomic per edge, atomic-free fill)
    zero_kernel<<<(N + BT - 1) / BT, BT, 0, stream>>>(cw, N);
    hist_kernel<<<(E + BT - 1) / BT, BT, 0, stream>>>(row, ew, cw, rank, E);
    scan1_kernel<<<NB, SCAN_B, 0, stream>>>(cw, rowptr, bsums, dis, N);
    scan2_kernel<<<1, SCAN_B, 0, stream>>>(bsums, NB);
    scan3_kernel<<<(N + BT - 1) / BT, BT, 0, stream>>>(rowptr, bsums, N, E);
    fill_kernel<<<(E + BT - 1) / BT, BT, 0, stream>>>(row, col, ew, dis, rowptr, rank, epack, E);

    // GEMM rows/block: F=100 -> NCG=25, ROWS=40; F=50 -> NCG=13, ROWS=76
    const int g100_blocks = (N + 39) / 40;
    const int g50_blocks  = (N + 75) / 76;

    const int agg100_blocks = 4 * ((N + 15) / 16);  // NCH=4
    const int agg50_blocks  = 2 * ((N + 15) / 16);  // NCH=2
    const int agg6_blocks   = (N * 8 + BT - 1) / BT;

    // ---- layer 0: x(128) -> 100 ----
    gemm_bf16_kernel<128, 100, false><<<g100_blocks, 256, 0, stream>>>(x, W0, bufA, N);
    agg_bf16_kernel<100, 4><<<agg100_blocks, BT, 0, stream>>>(rowptr, epack, (const unsigned int*)bufA, dis, b0, bufB, N);

    // ---- layer 1: 100 -> 100 ----
    gemm_bf16_kernel<100, 100, true><<<g100_blocks, 256, 0, stream>>>(bufB, W1, bufA, N);
    agg_bf16_kernel<100, 4><<<agg100_blocks, BT, 0, stream>>>(rowptr, epack, (const unsigned int*)bufA, dis, b1, bufB, N);

    // ---- layer 2: 100 -> 50 ----
    gemm_bf16_kernel<100, 50, true><<<g50_blocks, 256, 0, stream>>>(bufB, W2, bufA, N);
    agg_bf16_kernel<50, 2><<<agg50_blocks, BT, 0, stream>>>(rowptr, epack, (const unsigned int*)bufA, dis, b2, bufB, N);

    // ---- layer 3: 50 -> 6 ----
    gemv_rows_kernel<50, 6, true><<<(N + 255) / 256, 256, 0, stream>>>(bufB, W3, bufAf, N);
    agg_small_kernel<6, 8><<<agg6_blocks, BT, 0, stream>>>(rowptr, epack, bufAf, dis, b3, out, N);
}